// Round 7
// baseline (268.512 us; speedup 1.0000x reference)
//
#include <hip/hip_runtime.h>
#include <hip/hip_bf16.h>
#include <math.h>

// Problem constants
#define B 64
#define T 1000
#define RNN_DIM 1024
#define EMB_DIM 512
#define ATT_DIM 128
#define LOC_DIM 32
#define KSIZE 31
#define PAD 15          // SAME padding for K=31
#define ET 64           // t-positions per energy block (16 tiles, last partial)
#define CCH 20          // t-positions per context stage-1 block (50 chunks)
#define NCH (T / CCH)   // 50

// ---------------------------------------------------------------------------
// Kernel 1: pq[b][a] = dot(hidden[b, :1024], Wq[a, :1024])
// One wave per output. 8192 outputs -> 2048 blocks x 256 threads.
// ---------------------------------------------------------------------------
__global__ __launch_bounds__(256) void pq_kernel(
    const float* __restrict__ hidden,   // (B, 1024)
    const float* __restrict__ Wq,       // (128, 1024)
    float* __restrict__ pq)             // (B, 128)
{
    int gwave = (blockIdx.x * blockDim.x + threadIdx.x) >> 6;
    int lane  = threadIdx.x & 63;
    int b = gwave >> 7;     // / 128
    int a = gwave & 127;

    const float4* h4 = (const float4*)(hidden + (size_t)b * RNN_DIM);
    const float4* w4 = (const float4*)(Wq + (size_t)a * RNN_DIM);

    float acc = 0.f;
#pragma unroll
    for (int j = 0; j < 4; ++j) {
        float4 h = h4[j * 64 + lane];
        float4 w = w4[j * 64 + lane];
        acc += h.x * w.x + h.y * w.y + h.z * w.z + h.w * w.w;
    }
#pragma unroll
    for (int off = 32; off > 0; off >>= 1)
        acc += __shfl_down(acc, off, 64);
    if (lane == 0) pq[gwave] = acc;
}

// ---------------------------------------------------------------------------
// Kernel 2: fused location conv + W_loc projection + tanh + v-dot -> energy.
// Block = (b, 64-t tile), 256 threads, 3 barriers total.
// (R2 win: 78 us -> ~13 us; structure unchanged since.)
// ---------------------------------------------------------------------------
__global__ __launch_bounds__(256) void energy_kernel(
    const float* __restrict__ aw,       // (B, 2, T)
    const float* __restrict__ cw,       // (32, 2, 31)
    const float* __restrict__ wl,       // (128, 32)
    const float* __restrict__ pq,       // (B, 128)
    const float* __restrict__ pm,       // (B, T, 128)
    const float* __restrict__ v,        // (128)
    float* __restrict__ energy)         // (B, T)
{
    __shared__ float aw_lds[2][ET + 2 * PAD];     // [2][94]
    __shared__ float cw_lds[LOC_DIM][2][KSIZE];   // bank: 2-way, free
    __shared__ float wl_lds[ATT_DIM][36];         // stride 36: 4 distinct banks across aq
    __shared__ float pq_lds[ATT_DIM];
    __shared__ float v_lds[ATT_DIM];
    __shared__ float loc_lds[ET][36];             // stride 36: b128 reads 2-way (free)
    __shared__ float pm_lds[ET][132];             // stride 132: b32 reads 2-way (free)

    const int b   = blockIdx.x;
    const int t0  = blockIdx.y * ET;
    const int tid = threadIdx.x;

    // ---- stage pm tile: (64 t x 128 a) float4-coalesced (512B per row) ----
    const float4* pm4 = (const float4*)(pm + (size_t)b * T * ATT_DIM);
    for (int i = tid; i < ET * 32; i += 256) {
        int t = i >> 5, c4 = i & 31;
        int tt = t0 + t;
        float4 val = make_float4(0.f, 0.f, 0.f, 0.f);
        if (tt < T) val = pm4[(size_t)tt * 32 + c4];
        *((float4*)&pm_lds[t][c4 * 4]) = val;
    }
    // ---- stage small weights ----
    for (int i = tid; i < LOC_DIM * 2 * KSIZE; i += 256)
        ((float*)cw_lds)[i] = cw[i];
    for (int i = tid; i < ATT_DIM * LOC_DIM; i += 256)
        wl_lds[i >> 5][i & 31] = wl[i];
    if (tid < ATT_DIM) {
        pq_lds[tid] = pq[b * ATT_DIM + tid];
        v_lds[tid]  = v[tid];
    }
    for (int i = tid; i < 2 * (ET + 2 * PAD); i += 256) {
        int ch = i / (ET + 2 * PAD);
        int p  = i % (ET + 2 * PAD);
        int t  = t0 + p - PAD;
        aw_lds[ch][p] = (t >= 0 && t < T) ? aw[(size_t)b * 2 * T + ch * T + t] : 0.f;
    }
    __syncthreads();

    // ---- Phase 1: conv. thread = (c = tid&31, tg = tid>>5), 8 t's each ----
    {
        const int c  = tid & 31;
        const int tg = tid >> 5;
        float acc[8];
#pragma unroll
        for (int j = 0; j < 8; ++j) acc[j] = 0.f;
#pragma unroll
        for (int ch = 0; ch < 2; ++ch) {
            float awr[KSIZE + 7];   // 38-float sliding window in registers
#pragma unroll
            for (int j = 0; j < KSIZE + 7; ++j) awr[j] = aw_lds[ch][tg * 8 + j];
#pragma unroll
            for (int k = 0; k < KSIZE; ++k) {
                float cv = cw_lds[c][ch][k];   // 2-way broadcast, free
#pragma unroll
                for (int j = 0; j < 8; ++j) acc[j] += cv * awr[k + j];
            }
        }
#pragma unroll
        for (int j = 0; j < 8; ++j) loc_lds[tg * 8 + j][c] = acc[j];
    }
    __syncthreads();

    // ---- Phase 2: thread = (tl = tid>>2, aq = tid&3), a = aq + 4*aa ----
    {
        const int tl = tid >> 2;
        const int aq = tid & 3;

        float lr[32];   // loc row in registers
#pragma unroll
        for (int j = 0; j < 8; ++j)
            *((float4*)&lr[4 * j]) = *((const float4*)&loc_lds[tl][4 * j]);

        float acc = 0.f;
#pragma unroll 4
        for (int aa = 0; aa < 32; ++aa) {
            const int a = aq + 4 * aa;   // interleaved: 4 lanes -> 4 distinct banks
            float e = pq_lds[a] + pm_lds[tl][a];
#pragma unroll
            for (int j = 0; j < 8; ++j) {
                float4 w4 = *((const float4*)&wl_lds[a][4 * j]);
                e += w4.x * lr[4*j] + w4.y * lr[4*j+1] + w4.z * lr[4*j+2] + w4.w * lr[4*j+3];
            }
            // fast tanh: 1 - 2/(1+exp(2e)); ~5 VALU ops, abs err ~1e-6
            float ex = __expf(2.f * e);
            float th = 1.f - 2.f * __builtin_amdgcn_rcpf(1.f + ex);
            acc += v_lds[a] * th;
        }
        // reduce the 4 adjacent lanes sharing t
        acc += __shfl_xor(acc, 1, 64);
        acc += __shfl_xor(acc, 2, 64);
        if (aq == 0 && (t0 + tl) < T)
            energy[b * T + t0 + tl] = acc;
    }
}

// ---------------------------------------------------------------------------
// Kernel 3: softmax over T per batch row; writes weights to d_out tail.
// (ctx region is fully overwritten by context_sum_kernel - no zeroing needed.)
// ---------------------------------------------------------------------------
__global__ __launch_bounds__(256) void softmax_kernel(
    const float* __restrict__ energy,        // (B, T) in ws
    const unsigned char* __restrict__ mask,  // (B, T) bool
    float* __restrict__ out)                 // [B*512 ctx][B*1000 weights]
{
    int b   = blockIdx.x;
    int tid = threadIdx.x;

    __shared__ float red[4];
    float e[4];
    float mx = -INFINITY;
#pragma unroll
    for (int j = 0; j < 4; ++j) {
        int t = tid + j * 256;
        if (t < T) {
            float val = energy[b * T + t];
            if (mask[b * T + t]) val = -INFINITY;
            e[j] = val;
            mx = fmaxf(mx, val);
        } else e[j] = -INFINITY;
    }
#pragma unroll
    for (int off = 32; off > 0; off >>= 1)
        mx = fmaxf(mx, __shfl_down(mx, off, 64));
    if ((tid & 63) == 0) red[tid >> 6] = mx;
    __syncthreads();
    mx = fmaxf(fmaxf(red[0], red[1]), fmaxf(red[2], red[3]));
    __syncthreads();

    float sum = 0.f;
    float ex[4];
#pragma unroll
    for (int j = 0; j < 4; ++j) {
        ex[j] = (e[j] == -INFINITY) ? 0.f : expf(e[j] - mx);
        sum += ex[j];
    }
#pragma unroll
    for (int off = 32; off > 0; off >>= 1)
        sum += __shfl_down(sum, off, 64);
    if ((tid & 63) == 0) red[tid >> 6] = sum;
    __syncthreads();
    sum = red[0] + red[1] + red[2] + red[3];
    float inv = 1.f / sum;
#pragma unroll
    for (int j = 0; j < 4; ++j) {
        int t = tid + j * 256;
        if (t < T) out[B * EMB_DIM + b * T + t] = ex[j] * inv;
    }
}

// ---------------------------------------------------------------------------
// Kernel 4a: context partials. m13-copy-style streaming: wave = fixed
// (half-row h, t-parity tp); lane reads the consecutive float4 at
// t*128 + h*64 + lane  -- byte-identical shape to the measured 6.29 TB/s
// copy. Per-wave register accumulator, 1 barrier, plain coalesced partial
// store. NO atomics. Grid (64, 50) = 3200 blocks (~8/CU resident).
// ---------------------------------------------------------------------------
__global__ __launch_bounds__(256) void context_part_kernel(
    const float* __restrict__ memory,   // (B, T, 512)
    const float* __restrict__ w,        // weights at d_out + B*512
    float* __restrict__ part)           // (B, NCH, 512) in ws
{
    __shared__ float w_lds[CCH];
    __shared__ float4 red[4][64];

    const int b    = blockIdx.x;
    const int c    = blockIdx.y;
    const int t0   = c * CCH;
    const int tid  = threadIdx.x;
    const int lane = tid & 63;
    const int wv   = tid >> 6;
    const int h    = wv & 1;    // which 1-KB half of the 2-KB row
    const int tp   = wv >> 1;   // t parity

    if (tid < CCH) w_lds[tid] = w[b * T + t0 + tid];
    __syncthreads();

    const float4* mem4 = (const float4*)(memory + (size_t)b * T * EMB_DIM);
    float4 a0 = {0.f, 0.f, 0.f, 0.f};
    float4 a1 = {0.f, 0.f, 0.f, 0.f};
#pragma unroll
    for (int i = 0; i < CCH / 4; ++i) {     // 2 independent t-streams per wave
        int ta = t0 + tp + 4 * i;
        int tb = ta + 2;
        float wa = w_lds[tp + 4 * i];
        float wb = w_lds[tp + 4 * i + 2];
        float4 ma = mem4[(size_t)ta * 128 + h * 64 + lane];
        float4 mb = mem4[(size_t)tb * 128 + h * 64 + lane];
        a0.x += wa * ma.x; a0.y += wa * ma.y; a0.z += wa * ma.z; a0.w += wa * ma.w;
        a1.x += wb * mb.x; a1.y += wb * mb.y; a1.z += wb * mb.z; a1.w += wb * mb.w;
    }
    a0.x += a1.x; a0.y += a1.y; a0.z += a1.z; a0.w += a1.w;

    red[wv][lane] = a0;
    __syncthreads();
    if (tid < 128) {
        int hh = tid >> 6, e4 = tid & 63;
        float4 s0 = red[hh][e4];
        float4 s1 = red[hh + 2][e4];
        float4 s;
        s.x = s0.x + s1.x; s.y = s0.y + s1.y;
        s.z = s0.z + s1.z; s.w = s0.w + s1.w;
        float4* p4 = (float4*)(part + ((size_t)b * NCH + c) * EMB_DIM);
        p4[hh * 64 + e4] = s;
    }
}

// ---------------------------------------------------------------------------
// Kernel 4b: sum the 50 partials -> ctx. Grid (64, 2).
// R6 BUG FIX: 50 % 4 == 2, so the 4-stream loop must stop at 48; reading
// c=50,51 aliased batch b+1's chunks 0,1 (absmax 2.96e-2). Tail (48,49)
// is added explicitly.
// ---------------------------------------------------------------------------
__global__ __launch_bounds__(256) void context_sum_kernel(
    const float* __restrict__ part,     // (B, NCH, 512)
    float* __restrict__ ctx)            // d_out context region
{
    const int b = blockIdx.x;
    const int e = blockIdx.y * 256 + threadIdx.x;
    const float* p = part + (size_t)b * NCH * EMB_DIM + e;
    float s0 = 0.f, s1 = 0.f, s2 = 0.f, s3 = 0.f;
#pragma unroll
    for (int c = 0; c < NCH - 2; c += 4) {   // 48 chunks, 4 streams
        s0 += p[(c + 0) * EMB_DIM];
        s1 += p[(c + 1) * EMB_DIM];
        s2 += p[(c + 2) * EMB_DIM];
        s3 += p[(c + 3) * EMB_DIM];
    }
    s0 += p[(NCH - 2) * EMB_DIM];            // tail: chunks 48, 49
    s1 += p[(NCH - 1) * EMB_DIM];
    ctx[b * EMB_DIM + e] = (s0 + s1) + (s2 + s3);
}

// ---------------------------------------------------------------------------
extern "C" void kernel_launch(void* const* d_in, const int* in_sizes, int n_in,
                              void* d_out, int out_size, void* d_ws, size_t ws_size,
                              hipStream_t stream) {
    const float* hidden = (const float*)d_in[0];            // (64, 1024)
    const float* memory = (const float*)d_in[1];            // (64, 1000, 512)
    const float* pm     = (const float*)d_in[2];            // (64, 1000, 128)
    const float* aw     = (const float*)d_in[3];            // (64, 2, 1000)
    const unsigned char* mask = (const unsigned char*)d_in[4]; // (64, 1000) bool
    const float* Wq     = (const float*)d_in[5];            // (128, 1024)
    const float* cw     = (const float*)d_in[6];            // (32, 2, 31)
    const float* wl     = (const float*)d_in[7];            // (128, 32)
    const float* v      = (const float*)d_in[8];            // (1, 128)

    float* out = (float*)d_out;            // [B*512 context][B*1000 weights]

    // workspace layout
    float* pq_ws     = (float*)d_ws;                   // B*128
    float* energy_ws = pq_ws + B * ATT_DIM;            // B*T
    float* part_ws   = energy_ws + B * T;              // B*NCH*512 = 6.55 MB

    // 1) query projection: 8192 waves
    pq_kernel<<<dim3((B * ATT_DIM) / 4), dim3(256), 0, stream>>>(hidden, Wq, pq_ws);

    // 2) fused conv/proj/tanh/v-dot -> energy  (16 tiles of 64 t)
    energy_kernel<<<dim3(B, (T + ET - 1) / ET), dim3(256), 0, stream>>>(
        aw, cw, wl, pq_ws, pm, v, energy_ws);

    // 3) softmax (writes weights to out tail)
    softmax_kernel<<<dim3(B), dim3(256), 0, stream>>>(energy_ws, mask, out);

    // 4a) context partials (no atomics, m13-style streaming)
    context_part_kernel<<<dim3(B, NCH), dim3(256), 0, stream>>>(
        memory, out + B * EMB_DIM, part_ws);

    // 4b) partial sum -> ctx
    context_sum_kernel<<<dim3(B, 2), dim3(256), 0, stream>>>(part_ws, out);
}